// Round 2
// baseline (551.309 us; speedup 1.0000x reference)
//
#include <hip/hip_runtime.h>
#include <hip/hip_bf16.h>

#define NN 100000
#define NE 3200000
#define DI 128
#define DH 16
#define NB_SCAN 391   // ceil(NN/256)

// ---- edge index access: data may be int32 or int64 (JAX x64 flag unknown).
__device__ __forceinline__ int edge_src(const int* __restrict__ w, int is32, int e) {
    return is32 ? w[e] : w[2 * e];
}
__device__ __forceinline__ int edge_dst(const int* __restrict__ w, int is32, int e) {
    return is32 ? w[NE + e] : w[2 * (NE + e)];
}

__global__ __launch_bounds__(256) void detect_kernel(const unsigned int* __restrict__ w,
                                                     unsigned int* __restrict__ flag) {
    unsigned int v = 0;
    for (int i = threadIdx.x; i < 4096; i += 256) v |= w[2 * i + 1];
    if (v) atomicOr(flag, 1u);
}

__global__ __launch_bounds__(256) void deg_kernel(const int* __restrict__ ew,
                                                  const unsigned int* __restrict__ flag,
                                                  unsigned int* __restrict__ deg) {
    int e = blockIdx.x * 256 + threadIdx.x;
    int is32 = (*flag != 0);
    if (e < NE) {
        int d = edge_dst(ew, is32, e);
        if ((unsigned)d < NN) atomicAdd(&deg[d], 1u);
    }
}

__global__ __launch_bounds__(256) void dinv_kernel(const unsigned int* __restrict__ deg,
                                                   float* __restrict__ dinv) {
    int v = blockIdx.x * 256 + threadIdx.x;
    if (v < NN) dinv[v] = rsqrtf((float)(deg[v] + 1u));  // +1 = self loop
}

// ---- prefix scan of deg -> exclusive rowptr (3 small kernels) ----
__global__ __launch_bounds__(256) void scan1_kernel(const unsigned int* __restrict__ deg,
                                                    unsigned int* __restrict__ incl,
                                                    unsigned int* __restrict__ bsum) {
    __shared__ unsigned int s[256];
    int i = blockIdx.x * 256 + threadIdx.x;
    unsigned int v = (i < NN) ? deg[i] : 0u;
    s[threadIdx.x] = v;
    __syncthreads();
    for (int o = 1; o < 256; o <<= 1) {
        unsigned int t = (threadIdx.x >= o) ? s[threadIdx.x - o] : 0u;
        __syncthreads();
        s[threadIdx.x] += t;
        __syncthreads();
    }
    if (i < NN) incl[i] = s[threadIdx.x];
    if (threadIdx.x == 255) bsum[blockIdx.x] = s[255];
}

__global__ __launch_bounds__(512) void scan2_kernel(unsigned int* __restrict__ bsum) {
    __shared__ unsigned int s[512];
    unsigned int v = (threadIdx.x < NB_SCAN) ? bsum[threadIdx.x] : 0u;
    s[threadIdx.x] = v;
    __syncthreads();
    for (int o = 1; o < 512; o <<= 1) {
        unsigned int t = (threadIdx.x >= o) ? s[threadIdx.x - o] : 0u;
        __syncthreads();
        s[threadIdx.x] += t;
        __syncthreads();
    }
    if (threadIdx.x < NB_SCAN) bsum[threadIdx.x] = s[threadIdx.x] - v;  // exclusive
}

// rowptr[i] = incl_in_block - deg[i] + bsum_excl[blk]; cursor starts == rowptr
__global__ __launch_bounds__(256) void scan3_kernel(const unsigned int* __restrict__ deg,
                                                    const unsigned int* __restrict__ bsum,
                                                    unsigned int* __restrict__ rowptr,
                                                    unsigned int* __restrict__ cursor) {
    int i = blockIdx.x * 256 + threadIdx.x;
    if (i < NN) {
        unsigned int r = rowptr[i] - deg[i] + bsum[blockIdx.x];
        rowptr[i] = r;
        cursor[i] = r;
    }
}

// csr[pos] = src, bucketed by dst. cursor[v] ends at row end.
__global__ __launch_bounds__(256) void fill_kernel(const int* __restrict__ ew,
                                                   const unsigned int* __restrict__ flag,
                                                   unsigned int* __restrict__ cursor,
                                                   int* __restrict__ csr) {
    int e = blockIdx.x * 256 + threadIdx.x;
    int is32 = (*flag != 0);
    if (e < NE) {
        int s = edge_src(ew, is32, e);
        int d = edge_dst(ew, is32, e);
        if ((unsigned)s < NN && (unsigned)d < NN) {
            unsigned int pos = atomicAdd(&cursor[d], 1u);
            csr[pos] = s;
        }
    }
}

// g1[v][j] = (x[v] . W1[:,j]) * dinv[v]
__global__ __launch_bounds__(256) void gemm1_kernel(const float* __restrict__ x,
                                                    const float* __restrict__ W1,
                                                    const float* __restrict__ dinv,
                                                    float* __restrict__ g) {
    __shared__ float wl[DI * DH];
    __shared__ float xs[16 * 132];
    int tid = threadIdx.x;
    int n0 = blockIdx.x * 16;
    for (int i = tid; i < 512; i += 256)
        ((float4*)wl)[i] = ((const float4*)W1)[i];
    for (int i = tid; i < 512; i += 256) {
        int ln = i >> 5;
        int k4 = (i & 31) << 2;
        *(float4*)&xs[ln * 132 + k4] =
            *(const float4*)&x[(size_t)(n0 + ln) * DI + k4];
    }
    __syncthreads();
    int ln = tid >> 4, j = tid & 15;
    int v = n0 + ln;
    float acc = 0.f;
#pragma unroll
    for (int k = 0; k < DI; ++k)
        acc += xs[ln * 132 + k] * wl[k * 16 + j];
    g[v * 16 + j] = acc * dinv[v];
}

// out[v][f] = tanh(dinv[v]*(g[v][f] + sum_{e:dst=v} g[src][f]) + b[f])
__global__ __launch_bounds__(256) void gather_fin_kernel(const int* __restrict__ csr,
                                                         const unsigned int* __restrict__ rowptr,
                                                         const unsigned int* __restrict__ rowend,
                                                         const float* __restrict__ g,
                                                         const float* __restrict__ dinv,
                                                         const float* __restrict__ b,
                                                         float* __restrict__ out) {
    int tid = threadIdx.x;
    int v = blockIdx.x * 16 + (tid >> 4);
    int f = tid & 15;
    unsigned int i = rowptr[v], end = rowend[v];
    float sum = g[v * 16 + f];  // self loop
    for (; i + 4 <= end; i += 4) {
        int s0 = csr[i], s1 = csr[i + 1], s2 = csr[i + 2], s3 = csr[i + 3];
        sum += g[s0 * 16 + f];
        sum += g[s1 * 16 + f];
        sum += g[s2 * 16 + f];
        sum += g[s3 * 16 + f];
    }
    for (; i < end; ++i) sum += g[csr[i] * 16 + f];
    out[v * 16 + f] = tanhf(dinv[v] * sum + b[f]);
}

// g2[v][j] = (h1[v] @ W2[:,j]) * dinv[v]
__global__ __launch_bounds__(256) void gemm2_kernel(const float* __restrict__ h1,
                                                    const float* __restrict__ dinv,
                                                    const float* __restrict__ W2,
                                                    float* __restrict__ g2) {
    __shared__ float w2l[16 * 16];
    __shared__ float ht[16 * 17];
    int tid = threadIdx.x;
    w2l[tid] = W2[tid];
    int n0 = blockIdx.x * 16;
    int ln = tid >> 4, j = tid & 15;
    int v = n0 + ln;
    ht[ln * 17 + j] = h1[v * 16 + j];
    __syncthreads();
    float a = 0.f;
#pragma unroll
    for (int k = 0; k < 16; ++k)
        a += ht[ln * 17 + k] * w2l[k * 16 + j];
    g2[v * 16 + j] = a * dinv[v];
}

// ---------- round-1 fallback (atomic scatter) kernels ----------
__global__ __launch_bounds__(256) void scatter_kernel(const int* __restrict__ ew,
                                                      const unsigned int* __restrict__ flag,
                                                      const float* __restrict__ g,
                                                      float* __restrict__ acc) {
    unsigned int gid = blockIdx.x * 256u + threadIdx.x;
    int e = (int)(gid >> 4);
    int f = (int)(gid & 15u);
    int is32 = (*flag != 0);
    if (e < NE) {
        int s = edge_src(ew, is32, e);
        int d = edge_dst(ew, is32, e);
        if ((unsigned)s < NN && (unsigned)d < NN)
            unsafeAtomicAdd(&acc[d * 16 + f], g[s * 16 + f]);
    }
}

__global__ __launch_bounds__(256) void fin1_gemm2_kernel(const float* __restrict__ acc1,
                                                         const float* __restrict__ dinv,
                                                         const float* __restrict__ b1,
                                                         const float* __restrict__ W2,
                                                         float* __restrict__ g) {
    __shared__ float w2l[16 * 16];
    __shared__ float ht[16 * 17];
    int tid = threadIdx.x;
    w2l[tid] = W2[tid];
    int n0 = blockIdx.x * 16;
    int ln = tid >> 4, j = tid & 15;
    int v = n0 + ln;
    float di = dinv[v];
    float h = tanhf(di * (acc1[v * 16 + j] + g[v * 16 + j]) + b1[j]);
    ht[ln * 17 + j] = h;
    __syncthreads();
    float a = 0.f;
#pragma unroll
    for (int k = 0; k < 16; ++k)
        a += ht[ln * 17 + k] * w2l[k * 16 + j];
    g[v * 16 + j] = a * di;
}

__global__ __launch_bounds__(256) void fin2_kernel(const float* __restrict__ acc2,
                                                   const float* __restrict__ g2,
                                                   const float* __restrict__ dinv,
                                                   const float* __restrict__ b2,
                                                   float* __restrict__ out) {
    int i = blockIdx.x * 256 + threadIdx.x;
    if (i < NN * DH) {
        int v = i >> 4, j = i & 15;
        out[i] = tanhf(dinv[v] * (acc2[i] + g2[i]) + b2[j]);
    }
}

extern "C" void kernel_launch(void* const* d_in, const int* in_sizes, int n_in,
                              void* d_out, int out_size, void* d_ws, size_t ws_size,
                              hipStream_t stream) {
    const float* x  = (const float*)d_in[0];
    const int*   ew = (const int*)d_in[1];
    const float* W1 = (const float*)d_in[2];
    const float* b1 = (const float*)d_in[3];
    const float* W2 = (const float*)d_in[4];
    const float* b2 = (const float*)d_in[5];
    float* out = (float*)d_out;
    char* ws = (char*)d_ws;

    const size_t CSR_NEED = (15u << 20) + (size_t)NE * 4;  // ~27.3 MiB

    if (ws_size >= CSR_NEED) {
        // layout: flag@0, bsum@1K, deg@4K, rowptr@512K, cursor@1M,
        //         dinv@1.5M, g@2M (6.4M), h1@8.5M (6.4M), csr@15M (12.8M)
        unsigned int* flag   = (unsigned int*)(ws);
        unsigned int* bsum   = (unsigned int*)(ws + 1024);
        unsigned int* deg    = (unsigned int*)(ws + 4096);
        unsigned int* rowptr = (unsigned int*)(ws + (512u << 10));
        unsigned int* cursor = (unsigned int*)(ws + (1u << 20));
        float* dinv = (float*)(ws + ((1u << 20) + (512u << 10)));
        float* g    = (float*)(ws + (2u << 20));
        float* h1   = (float*)(ws + ((8u << 20) + (512u << 10)));
        int*   csr  = (int*)(ws + (15u << 20));

        hipMemsetAsync(ws, 0, 4096 + NN * 4, stream);  // flag, bsum, deg

        detect_kernel<<<1, 256, 0, stream>>>((const unsigned int*)ew, flag);
        deg_kernel<<<(NE + 255) / 256, 256, 0, stream>>>(ew, flag, deg);
        dinv_kernel<<<NB_SCAN, 256, 0, stream>>>(deg, dinv);
        scan1_kernel<<<NB_SCAN, 256, 0, stream>>>(deg, rowptr, bsum);
        scan2_kernel<<<1, 512, 0, stream>>>(bsum);
        scan3_kernel<<<NB_SCAN, 256, 0, stream>>>(deg, bsum, rowptr, cursor);
        fill_kernel<<<(NE + 255) / 256, 256, 0, stream>>>(ew, flag, cursor, csr);
        gemm1_kernel<<<NN / 16, 256, 0, stream>>>(x, W1, dinv, g);
        gather_fin_kernel<<<NN / 16, 256, 0, stream>>>(csr, rowptr, cursor, g, dinv, b1, h1);
        gemm2_kernel<<<NN / 16, 256, 0, stream>>>(h1, dinv, W2, g);
        gather_fin_kernel<<<NN / 16, 256, 0, stream>>>(csr, rowptr, cursor, g, dinv, b2, out);
    } else {
        // round-1 atomic-scatter fallback (~23.4 MiB)
        unsigned int* flag = (unsigned int*)(ws);
        unsigned int* deg  = (unsigned int*)(ws + (1u << 20));
        float* acc1 = (float*)(ws + (2u << 20));
        float* acc2 = (float*)(ws + (9u << 20));
        float* dinv = (float*)(ws + (16u << 20));
        float* g    = (float*)(ws + (17u << 20));

        hipMemsetAsync(ws, 0, (16u << 20), stream);

        detect_kernel<<<1, 256, 0, stream>>>((const unsigned int*)ew, flag);
        deg_kernel<<<(NE + 255) / 256, 256, 0, stream>>>(ew, flag, deg);
        dinv_kernel<<<(NN + 255) / 256, 256, 0, stream>>>(deg, dinv);
        gemm1_kernel<<<NN / 16, 256, 0, stream>>>(x, W1, dinv, g);
        scatter_kernel<<<NE * 16 / 256, 256, 0, stream>>>(ew, flag, g, acc1);
        fin1_gemm2_kernel<<<NN / 16, 256, 0, stream>>>(acc1, dinv, b1, W2, g);
        scatter_kernel<<<NE * 16 / 256, 256, 0, stream>>>(ew, flag, g, acc2);
        fin2_kernel<<<NN * DH / 256, 256, 0, stream>>>(acc2, g, dinv, b2, out);
    }
}